// Round 3
// baseline (596.319 us; speedup 1.0000x reference)
//
#include <hip/hip_runtime.h>

#define Fdim 128
#define Bsz  8192
#define Pn   6
#define EPSI 1e-5f
#define MROWS 64      // m-rows per block
#define XPITCH 136    // 128 + 8 halves pad (272 B row stride, 16B-aligned)

typedef _Float16 half8  __attribute__((ext_vector_type(8)));
typedef _Float16 half4t __attribute__((ext_vector_type(4)));
typedef float    float4t __attribute__((ext_vector_type(4)));

__constant__ int PAIR_A[6] = {0,0,0,1,1,2};
__constant__ int PAIR_B[6] = {1,2,3,2,3,3};

// ---------------------------------------------------------------------------
// Kernel 1: W [128 x 16384] fp32 -> f16, swizzled into MFMA B-fragment order.
// mfma_f32_16x16x32_f16 B-operand: lane = q*16 + ol holds
// B[k = c*32 + q*8 + jj][n = nt*16 + ol], jj = 0..7 (one half8 per lane).
// Wws half8 index = c*512 + nt*64 + lane.
// ---------------------------------------------------------------------------
__global__ __launch_bounds__(256) void wprep(const float* __restrict__ W,
                                             _Float16* __restrict__ Wws) {
    int t  = blockIdx.x * 256 + threadIdx.x;   // 0 .. 262143  (= 128 * 2048)
    int o  = t >> 11;                          // 0..127
    int kg = t & 2047;                         // group of 8 k's
    int k0 = kg << 3;
    int c  = kg >> 2;                          // k-chunk of 32
    int q  = kg & 3;
    int nt = o >> 4;
    int ol = o & 15;
    const float4t* src = (const float4t*)(W + (size_t)o * 16384 + k0);
    float4t a0 = src[0];
    float4t a1 = src[1];
    half8 h;
    h[0] = (_Float16)a0[0]; h[1] = (_Float16)a0[1];
    h[2] = (_Float16)a0[2]; h[3] = (_Float16)a0[3];
    h[4] = (_Float16)a1[0]; h[5] = (_Float16)a1[1];
    h[6] = (_Float16)a1[2]; h[7] = (_Float16)a1[3];
    *(half8*)(Wws + ((size_t)(c * 8 + nt) * 64 + q * 16 + ol) * 8) = h;
}

// ---------------------------------------------------------------------------
// Kernel 2: per (pair, 64-row m-block) GEMM over full 128-n. 4 waves; each
// wave owns 2 n-tiles (w, w+4) sharing one on-the-fly A-fragment
// A'[b, i*128+j] = x1[b,i]*x2[b,j]  (x2-frag register-cached per j-chunk,
// scaled by scalar x1[b,i]). No barriers in the K-loop; W streams
// global->register (L2-resident). Per-(pair,o) sum/sumsq via shuffle+atomics.
// LDS 34.8 KB -> 4 blocks/CU capacity; grid 768 = 3 resident/CU, one round.
// ---------------------------------------------------------------------------
__global__ __launch_bounds__(256, 4) void gemm(const float* __restrict__ x,
                                               const _Float16* __restrict__ Wws,
                                               _Float16* __restrict__ yws,
                                               float* __restrict__ ssum,
                                               float* __restrict__ ssq) {
    __shared__ _Float16 x1t[MROWS * XPITCH];
    __shared__ _Float16 x2t[MROWS * XPITCH];

    int bid  = blockIdx.x;
    int p    = bid >> 7;          // pair 0..5
    int mblk = bid & 127;         // 128 m-blocks of 64 rows
    int m0   = mblk * MROWS;
    int v1   = PAIR_A[p];
    int v2   = PAIR_B[p];
    int tid  = threadIdx.x;

    // ---- stage x1 / x2 tiles (fp32 -> f16), padded rows -------------------
    {
        const float4t* s1p = (const float4t*)(x + ((size_t)v1 * Bsz + m0) * Fdim);
        const float4t* s2p = (const float4t*)(x + ((size_t)v2 * Bsz + m0) * Fdim);
        for (int r = 0; r < 8; ++r) {
            int idx = r * 256 + tid;          // float4 index; 2048 per tile
            int row = idx >> 5;
            int col = (idx & 31) * 4;
            float4t a = s1p[idx];
            half4t h1; h1[0]=(_Float16)a[0]; h1[1]=(_Float16)a[1];
                       h1[2]=(_Float16)a[2]; h1[3]=(_Float16)a[3];
            *(half4t*)&x1t[row * XPITCH + col] = h1;
            float4t b = s2p[idx];
            half4t h2; h2[0]=(_Float16)b[0]; h2[1]=(_Float16)b[1];
                       h2[2]=(_Float16)b[2]; h2[3]=(_Float16)b[3];
            *(half4t*)&x2t[row * XPITCH + col] = h2;
        }
    }
    __syncthreads();

    int lane  = tid & 63;
    int w     = tid >> 6;         // wave 0..3
    int ol    = lane & 15;
    int q     = lane >> 4;
    int nt0   = w;                // n-tiles owned by this wave
    int nt1   = w + 4;

    float4t acc[4][2];
#pragma unroll
    for (int mt = 0; mt < 4; ++mt) {
        acc[mt][0] = (float4t){0.f, 0.f, 0.f, 0.f};
        acc[mt][1] = (float4t){0.f, 0.f, 0.f, 0.f};
    }

    const half8* wb = (const half8*)Wws;
    const size_t woff0 = (size_t)nt0 * 64 + lane;   // half8 units
    const size_t woff1 = (size_t)nt1 * 64 + lane;

    for (int jc = 0; jc < 4; ++jc) {
        // x2 fragments for this j-chunk: constant across the whole i-sweep
        half8 x2f[4];
#pragma unroll
        for (int mt = 0; mt < 4; ++mt)
            x2f[mt] = *(const half8*)&x2t[(mt * 16 + ol) * XPITCH + jc * 32 + q * 8];

        // b-fragment prefetch pipeline, distance 2 (k-chunk c = i*4 + jc)
        half8 bfa0 = wb[(size_t)(0 * 4 + jc) * 512 + woff0];
        half8 bfa1 = wb[(size_t)(0 * 4 + jc) * 512 + woff1];
        half8 bfb0 = wb[(size_t)(1 * 4 + jc) * 512 + woff0];
        half8 bfb1 = wb[(size_t)(1 * 4 + jc) * 512 + woff1];

        for (int i8 = 0; i8 < 16; ++i8) {
            half8 x1f[4];
#pragma unroll
            for (int mt = 0; mt < 4; ++mt)
                x1f[mt] = *(const half8*)&x1t[(mt * 16 + ol) * XPITCH + i8 * 8];
#pragma unroll
            for (int ii = 0; ii < 8; ++ii) {
                int i  = i8 * 8 + ii;
                int ip = (i < 126) ? (i + 2) : 127;
                half8 bn0 = wb[(size_t)(ip * 4 + jc) * 512 + woff0];
                half8 bn1 = wb[(size_t)(ip * 4 + jc) * 512 + woff1];
#pragma unroll
                for (int mt = 0; mt < 4; ++mt) {
                    _Float16 sc = x1f[mt][ii];
                    half8 a = x2f[mt] * sc;         // 4x v_pk_mul_f16, shared by 2 MFMAs
                    acc[mt][0] = __builtin_amdgcn_mfma_f32_16x16x32_f16(a, bfa0, acc[mt][0], 0, 0, 0);
                    acc[mt][1] = __builtin_amdgcn_mfma_f32_16x16x32_f16(a, bfa1, acc[mt][1], 0, 0, 0);
                }
                bfa0 = bfb0; bfa1 = bfb1;
                bfb0 = bn0;  bfb1 = bn1;
            }
        }
    }

    // ---- epilogue: store y (f16) + per-o stats ----------------------------
    float sum0 = 0.f, sq0 = 0.f, sum1 = 0.f, sq1 = 0.f;
    int col0 = nt0 * 16 + ol;
    int col1 = nt1 * 16 + ol;
#pragma unroll
    for (int mt = 0; mt < 4; ++mt) {
#pragma unroll
        for (int r = 0; r < 4; ++r) {
            size_t row = (size_t)p * Bsz + m0 + mt * 16 + q * 4 + r;
            float v0 = acc[mt][0][r];
            sum0 += v0; sq0 += v0 * v0;
            yws[row * Fdim + col0] = (_Float16)v0;
            float v1e = acc[mt][1][r];
            sum1 += v1e; sq1 += v1e * v1e;
            yws[row * Fdim + col1] = (_Float16)v1e;
        }
    }
    sum0 += __shfl_xor(sum0, 16, 64);  sum0 += __shfl_xor(sum0, 32, 64);
    sq0  += __shfl_xor(sq0, 16, 64);   sq0  += __shfl_xor(sq0, 32, 64);
    sum1 += __shfl_xor(sum1, 16, 64);  sum1 += __shfl_xor(sum1, 32, 64);
    sq1  += __shfl_xor(sq1, 16, 64);   sq1  += __shfl_xor(sq1, 32, 64);
    if (q == 0) {
        atomicAdd(&ssum[p * Fdim + col0], sum0);
        atomicAdd(&ssq [p * Fdim + col0], sq0);
        atomicAdd(&ssum[p * Fdim + col1], sum1);
        atomicAdd(&ssq [p * Fdim + col1], sq1);
    }
}

// ---------------------------------------------------------------------------
// Kernel 3: BN (train-mode batch stats, biased var) + ReLU, f16 y -> fp32 out.
// ---------------------------------------------------------------------------
__global__ __launch_bounds__(256) void bnrelu(const _Float16* __restrict__ yws,
                                              const float* __restrict__ ssum,
                                              const float* __restrict__ ssq,
                                              const float* __restrict__ gamma,
                                              const float* __restrict__ beta,
                                              float* __restrict__ out) {
    __shared__ float gs[128], sh[128];
    size_t ebase = (size_t)blockIdx.x * 1024;
    int p = (int)(ebase >> 20);            // B*F = 2^20
    int t = threadIdx.x;
    if (t < 128) {
        float mean = ssum[p * Fdim + t] * (1.0f / 8192.0f);
        float var  = ssq [p * Fdim + t] * (1.0f / 8192.0f) - mean * mean;
        float g    = gamma[t] * rsqrtf(var + EPSI);
        gs[t] = g;
        sh[t] = beta[t] - g * mean;
    }
    __syncthreads();
    size_t e0 = ebase + (size_t)t * 4;
    int o0 = (int)(e0 & 127);
    half4t y = *(const half4t*)(yws + e0);
    float4t r;
#pragma unroll
    for (int l = 0; l < 4; ++l) {
        float v = fmaf(gs[o0 + l], (float)y[l], sh[o0 + l]);
        r[l] = v > 0.f ? v : 0.f;
    }
    *(float4t*)(out + e0) = r;
}

// ---------------------------------------------------------------------------
extern "C" void kernel_launch(void* const* d_in, const int* in_sizes, int n_in,
                              void* d_out, int out_size, void* d_ws, size_t ws_size,
                              hipStream_t stream) {
    const float* x     = (const float*)d_in[0];
    const float* W     = (const float*)d_in[1];
    // d_in[2] = linear bias b: mathematically cancelled by train-mode BN.
    const float* gamma = (const float*)d_in[3];
    const float* beta  = (const float*)d_in[4];
    float* out = (float*)d_out;

    char* ws = (char*)d_ws;
    _Float16* yws = (_Float16*)ws;                       // 6*8192*128*2 = 12,582,912 B
    _Float16* Wws = (_Float16*)(ws + 12582912);          // 128*16384*2  =  4,194,304 B
    float*    ssum = (float*)(ws + 16777216);            // 768 floats
    float*    ssq  = ssum + Pn * Fdim;                   // 768 floats

    (void)hipMemsetAsync(ssum, 0, 2 * Pn * Fdim * sizeof(float), stream);
    wprep<<<1024, 256, 0, stream>>>(W, Wws);
    gemm<<<768, 256, 0, stream>>>(x, Wws, yws, ssum, ssq);
    bnrelu<<<6144, 256, 0, stream>>>(yws, ssum, ssq, gamma, beta, out);
}

// Round 4
// 312.760 us; speedup vs baseline: 1.9066x; 1.9066x over previous
//
#include <hip/hip_runtime.h>

#define Fdim 128
#define Bsz  8192
#define Pn   6
#define EPSI 1e-5f
#define XPITCH 132    // 128 + 4 halves pad (264 B row stride; ol-lanes hit 16 distinct banks, q broadcasts)

typedef _Float16 half8  __attribute__((ext_vector_type(8)));
typedef _Float16 half4t __attribute__((ext_vector_type(4)));
typedef float    float4t __attribute__((ext_vector_type(4)));

__constant__ int PAIR_A[6] = {0,0,0,1,1,2};
__constant__ int PAIR_B[6] = {1,2,3,2,3,3};

// ---------------------------------------------------------------------------
// Kernel 1: W [128 x 16384] fp32 -> f16, swizzled into MFMA B-fragment order.
// mfma_f32_16x16x32_f16 B-operand: lane = q*16 + ol holds
// B[k = c*32 + q*8 + jj][n = nt*16 + ol], jj = 0..7 (one half8 per lane).
// Wws half8 index = c*512 + nt*64 + lane.
// ---------------------------------------------------------------------------
__global__ __launch_bounds__(256) void wprep(const float* __restrict__ W,
                                             _Float16* __restrict__ Wws) {
    int t  = blockIdx.x * 256 + threadIdx.x;   // 0 .. 262143  (= 128 * 2048)
    int o  = t >> 11;                          // 0..127
    int kg = t & 2047;                         // group of 8 k's
    int k0 = kg << 3;
    int c  = kg >> 2;                          // k-chunk of 32
    int q  = kg & 3;
    int nt = o >> 4;
    int ol = o & 15;
    const float4t* src = (const float4t*)(W + (size_t)o * 16384 + k0);
    float4t a0 = src[0];
    float4t a1 = src[1];
    half8 h;
    h[0] = (_Float16)a0[0]; h[1] = (_Float16)a0[1];
    h[2] = (_Float16)a0[2]; h[3] = (_Float16)a0[3];
    h[4] = (_Float16)a1[0]; h[5] = (_Float16)a1[1];
    h[6] = (_Float16)a1[2]; h[7] = (_Float16)a1[3];
    *(half8*)(Wws + ((size_t)(c * 8 + nt) * 64 + q * 16 + ol) * 8) = h;
}

// ---------------------------------------------------------------------------
// Kernel 2: per (pair, 128-row m-block, 64-col n-half) GEMM.
// W traffic = 6 * 64 mblocks * 2 nh * 2MB = 1.5 GB total -> L2/LLC-absorbed
// (R2-proven: FETCH 44 MB). On-the-fly A: A'[b, i*128+j] = x1[b,i]*x2[b,j];
// x1 tile staged in LDS (f16, padded); x2 fragments re-read from GLOBAL fp32
// once per jc-pass (tile read exactly once/block) -> LDS = 33.8 KB ->
// grid 768 = exactly 3 resident blocks/CU, single round, no tail.
// ---------------------------------------------------------------------------
__global__ __launch_bounds__(256, 3) void gemm(const float* __restrict__ x,
                                               const _Float16* __restrict__ Wws,
                                               _Float16* __restrict__ yws,
                                               float* __restrict__ ssum,
                                               float* __restrict__ ssq) {
    __shared__ _Float16 x1t[128 * XPITCH];

    int bid  = blockIdx.x;
    int p    = bid >> 7;          // pair 0..5
    int rem  = bid & 127;
    int mblk = rem >> 1;          // 64 m-blocks of 128 rows
    int nh   = rem & 1;
    int m0   = mblk * 128;
    int v1   = PAIR_A[p];
    int v2   = PAIR_B[p];
    int tid  = threadIdx.x;

    // ---- stage x1 tile (fp32 -> f16), padded rows -------------------------
    {
        const float4t* s1p = (const float4t*)(x + ((size_t)v1 * Bsz + m0) * Fdim);
        for (int r = 0; r < 16; ++r) {
            int idx = r * 256 + tid;          // float4 index; 4096 per tile
            int row = idx >> 5;
            int col = (idx & 31) * 4;
            float4t a = s1p[idx];
            half4t h1; h1[0]=(_Float16)a[0]; h1[1]=(_Float16)a[1];
                       h1[2]=(_Float16)a[2]; h1[3]=(_Float16)a[3];
            *(half4t*)&x1t[row * XPITCH + col] = h1;
        }
    }
    __syncthreads();

    int lane  = tid & 63;
    int w     = tid >> 6;         // wave 0..3 -> n-tile within the half
    int ol    = lane & 15;
    int q     = lane >> 4;
    int obase = nh * 64 + w * 16;
    int nt_g  = (nh << 2) + w;    // global 16-wide n-tile index 0..7

    float4t acc[8];
#pragma unroll
    for (int mt = 0; mt < 8; ++mt) acc[mt] = (float4t){0.f, 0.f, 0.f, 0.f};

    const half8* wb = (const half8*)Wws;
    const size_t woff = (size_t)nt_g * 64 + lane;   // half8 units
    const float* x2base = x + ((size_t)v2 * Bsz + m0) * Fdim;

    for (int jc = 0; jc < 4; ++jc) {
        // x2 fragments for this j-chunk, straight from global fp32:
        // lane (q,ol) in m-tile mt needs x2[mt*16+ol, jc*32+q*8 .. +7].
        half8 x2f[8];
#pragma unroll
        for (int mt = 0; mt < 8; ++mt) {
            const float4t* sp = (const float4t*)(x2base + (size_t)(mt * 16 + ol) * Fdim
                                                 + jc * 32 + q * 8);
            float4t a0 = sp[0];
            float4t a1 = sp[1];
            half8 h;
            h[0] = (_Float16)a0[0]; h[1] = (_Float16)a0[1];
            h[2] = (_Float16)a0[2]; h[3] = (_Float16)a0[3];
            h[4] = (_Float16)a1[0]; h[5] = (_Float16)a1[1];
            h[6] = (_Float16)a1[2]; h[7] = (_Float16)a1[3];
            x2f[mt] = h;
        }

        // b-fragment prefetch pipeline, distance 2 (k-chunk c = i*4 + jc)
        half8 bf0 = wb[(size_t)(0 * 4 + jc) * 512 + woff];
        half8 bf1 = wb[(size_t)(1 * 4 + jc) * 512 + woff];

        for (int i8 = 0; i8 < 16; ++i8) {
            half8 x1f[8];
#pragma unroll
            for (int mt = 0; mt < 8; ++mt)
                x1f[mt] = *(const half8*)&x1t[(mt * 16 + ol) * XPITCH + i8 * 8];
#pragma unroll
            for (int ii = 0; ii < 8; ++ii) {
                int i  = i8 * 8 + ii;
                int ip = (i < 126) ? (i + 2) : 127;
                half8 bn = wb[(size_t)(ip * 4 + jc) * 512 + woff];
#pragma unroll
                for (int mt = 0; mt < 8; ++mt) {
                    _Float16 sc = x1f[mt][ii];
                    half8 a = x2f[mt] * sc;         // 4x v_pk_mul_f16
                    acc[mt] = __builtin_amdgcn_mfma_f32_16x16x32_f16(a, bf0, acc[mt], 0, 0, 0);
                }
                bf0 = bf1;
                bf1 = bn;
            }
        }
    }

    // ---- epilogue: store y (f16) + per-o stats ----------------------------
    float sum0 = 0.f, sq0 = 0.f;
#pragma unroll
    for (int mt = 0; mt < 8; ++mt) {
#pragma unroll
        for (int r = 0; r < 4; ++r) {
            float v = acc[mt][r];
            sum0 += v;
            sq0  += v * v;
            size_t row = (size_t)p * Bsz + m0 + mt * 16 + q * 4 + r;
            yws[row * Fdim + obase + ol] = (_Float16)v;
        }
    }
    sum0 += __shfl_xor(sum0, 16, 64);  sum0 += __shfl_xor(sum0, 32, 64);
    sq0  += __shfl_xor(sq0, 16, 64);   sq0  += __shfl_xor(sq0, 32, 64);
    if (q == 0) {
        atomicAdd(&ssum[p * Fdim + obase + ol], sum0);
        atomicAdd(&ssq [p * Fdim + obase + ol], sq0);
    }
}

// ---------------------------------------------------------------------------
// Kernel 3: BN (train-mode batch stats, biased var) + ReLU, f16 y -> fp32 out.
// ---------------------------------------------------------------------------
__global__ __launch_bounds__(256) void bnrelu(const _Float16* __restrict__ yws,
                                              const float* __restrict__ ssum,
                                              const float* __restrict__ ssq,
                                              const float* __restrict__ gamma,
                                              const float* __restrict__ beta,
                                              float* __restrict__ out) {
    __shared__ float gs[128], sh[128];
    size_t ebase = (size_t)blockIdx.x * 1024;
    int p = (int)(ebase >> 20);            // B*F = 2^20
    int t = threadIdx.x;
    if (t < 128) {
        float mean = ssum[p * Fdim + t] * (1.0f / 8192.0f);
        float var  = ssq [p * Fdim + t] * (1.0f / 8192.0f) - mean * mean;
        float g    = gamma[t] * rsqrtf(var + EPSI);
        gs[t] = g;
        sh[t] = beta[t] - g * mean;
    }
    __syncthreads();
    size_t e0 = ebase + (size_t)t * 4;
    int o0 = (int)(e0 & 127);
    half4t y = *(const half4t*)(yws + e0);
    float4t r;
#pragma unroll
    for (int l = 0; l < 4; ++l) {
        float v = fmaf(gs[o0 + l], (float)y[l], sh[o0 + l]);
        r[l] = v > 0.f ? v : 0.f;
    }
    *(float4t*)(out + e0) = r;
}

// ---------------------------------------------------------------------------
extern "C" void kernel_launch(void* const* d_in, const int* in_sizes, int n_in,
                              void* d_out, int out_size, void* d_ws, size_t ws_size,
                              hipStream_t stream) {
    const float* x     = (const float*)d_in[0];
    const float* W     = (const float*)d_in[1];
    // d_in[2] = linear bias b: mathematically cancelled by train-mode BN.
    const float* gamma = (const float*)d_in[3];
    const float* beta  = (const float*)d_in[4];
    float* out = (float*)d_out;

    char* ws = (char*)d_ws;
    _Float16* yws = (_Float16*)ws;                       // 6*8192*128*2 = 12,582,912 B
    _Float16* Wws = (_Float16*)(ws + 12582912);          // 128*16384*2  =  4,194,304 B
    float*    ssum = (float*)(ws + 16777216);            // 768 floats
    float*    ssq  = ssum + Pn * Fdim;                   // 768 floats

    (void)hipMemsetAsync(ssum, 0, 2 * Pn * Fdim * sizeof(float), stream);
    wprep<<<1024, 256, 0, stream>>>(W, Wws);
    gemm<<<768, 256, 0, stream>>>(x, Wws, yws, ssum, ssq);
    bnrelu<<<6144, 256, 0, stream>>>(yws, ssum, ssq, gamma, beta, out);
}

// Round 5
// 258.852 us; speedup vs baseline: 2.3037x; 1.2083x over previous
//
#include <hip/hip_runtime.h>

#define Fdim 128
#define Bsz  8192
#define Pn   6
#define EPSI 1e-5f
#define X2P 136       // x2 tile pitch (halves): 272 B rows, R2-proven (~0.4M conflicts, negligible)
#define X1P 72        // x1 half-tile pitch: 144 B rows -> 2-way max on ds_read_b128 (free)

typedef _Float16 half8  __attribute__((ext_vector_type(8)));
typedef _Float16 half4t __attribute__((ext_vector_type(4)));
typedef float    float4t __attribute__((ext_vector_type(4)));

__constant__ int PAIR_A[6] = {0,0,0,1,1,2};
__constant__ int PAIR_B[6] = {1,2,3,2,3,3};

// ---------------------------------------------------------------------------
// Kernel 1: W [128 x 16384] fp32 -> f16 MFMA B-fragments.
// lane = q*16+ol holds B[k=c*32+q*8+jj][n=nt*16+ol]; Wws half8 idx = c*512+nt*64+lane.
// Thread map: t = c*512 + nt*64 + lane -> stores are wave-contiguous (1 KB/wave).
// ---------------------------------------------------------------------------
__global__ __launch_bounds__(256) void wprep(const float* __restrict__ W,
                                             _Float16* __restrict__ Wws) {
    int t    = blockIdx.x * 256 + threadIdx.x;  // 0..262143 = 512 c * 8 nt * 64 lane
    int c    = t >> 9;
    int r    = t & 511;
    int nt   = r >> 6;
    int lane = r & 63;
    int q    = lane >> 4;
    int ol   = lane & 15;
    int o    = nt * 16 + ol;
    const float4t* src = (const float4t*)(W + (size_t)o * 16384 + c * 32 + q * 8);
    float4t a0 = src[0];
    float4t a1 = src[1];
    half8 h;
    h[0] = (_Float16)a0[0]; h[1] = (_Float16)a0[1];
    h[2] = (_Float16)a0[2]; h[3] = (_Float16)a0[3];
    h[4] = (_Float16)a1[0]; h[5] = (_Float16)a1[1];
    h[6] = (_Float16)a1[2]; h[7] = (_Float16)a1[3];
    *(half8*)(Wws + (size_t)t * 8) = h;
}

// ---------------------------------------------------------------------------
// Kernel 2: per (pair, 128-row m-block, 64-col n-half). R2's per-wave K-loop
// (4mt x 2nt sharing one on-the-fly A-frag; 2 pk_mul + 256B W per MFMA) with
// LDS cut to 52 KB via i-halved x1 staging -> 3 blocks/CU, grid 768 = one
// round, zero tail. Wave grid 2x2: wrow = m-half, wcol = nt-pair.
// ---------------------------------------------------------------------------
__global__ __launch_bounds__(256, 3) void gemm(const float* __restrict__ x,
                                               const _Float16* __restrict__ Wws,
                                               _Float16* __restrict__ yws,
                                               float* __restrict__ ssum,
                                               float* __restrict__ ssq) {
    __shared__ _Float16 x2t[128 * X2P];    // 34816 B: full 128 rows x 128 j
    __shared__ _Float16 x1th[128 * X1P];   // 18432 B: 128 rows x 64 i (one half)

    int bid  = blockIdx.x;
    int p    = bid >> 7;
    int rem  = bid & 127;
    int mblk = rem >> 1;          // 64 m-blocks of 128 rows
    int nh   = rem & 1;
    int m0   = mblk * 128;
    int v1   = PAIR_A[p];
    int v2   = PAIR_B[p];
    int tid  = threadIdx.x;

    // ---- stage x2 tile (full 128x128, fp32 -> f16) ------------------------
    {
        const float4t* s2p = (const float4t*)(x + ((size_t)v2 * Bsz + m0) * Fdim);
        for (int it = 0; it < 16; ++it) {
            int idx = it * 256 + tid;
            int row = idx >> 5;
            int col = (idx & 31) * 4;
            float4t b = s2p[idx];
            half4t h2; h2[0]=(_Float16)b[0]; h2[1]=(_Float16)b[1];
                       h2[2]=(_Float16)b[2]; h2[3]=(_Float16)b[3];
            *(half4t*)&x2t[row * X2P + col] = h2;
        }
    }

    int lane  = tid & 63;
    int w     = tid >> 6;
    int wrow  = w >> 1;           // m-half: rows wrow*64 + mt*16 + ...
    int wcol  = w & 1;            // nt pair within the n-half
    int ol    = lane & 15;
    int q     = lane >> 4;
    int ntg0  = nh * 4 + wcol * 2;    // global 16-wide n-tiles
    int ntg1  = ntg0 + 1;
    int rbase = wrow * 64;

    float4t acc[4][2];
#pragma unroll
    for (int mt = 0; mt < 4; ++mt) {
        acc[mt][0] = (float4t){0.f, 0.f, 0.f, 0.f};
        acc[mt][1] = (float4t){0.f, 0.f, 0.f, 0.f};
    }

    const half8* wb = (const half8*)Wws;
    const size_t woff0 = (size_t)ntg0 * 64 + lane;
    const size_t woff1 = (size_t)ntg1 * 64 + lane;
    const float* x1src = x + ((size_t)v1 * Bsz + m0) * Fdim;

    for (int kh = 0; kh < 2; ++kh) {
        if (kh) __syncthreads();      // all reads of previous x1 half done
        // ---- stage x1 half-tile: 128 rows x 64 i-cols ---------------------
        for (int it = 0; it < 8; ++it) {
            int idx = it * 256 + tid;
            int row = idx >> 4;
            int c4  = (idx & 15) * 4;
            float4t a = *(const float4t*)(x1src + (size_t)row * Fdim + kh * 64 + c4);
            half4t h1; h1[0]=(_Float16)a[0]; h1[1]=(_Float16)a[1];
                       h1[2]=(_Float16)a[2]; h1[3]=(_Float16)a[3];
            *(half4t*)&x1th[row * X1P + c4] = h1;
        }
        __syncthreads();

        int ibase = kh * 64;          // global i of this half
        for (int jc = 0; jc < 4; ++jc) {
            // x2 fragments: constant across the whole i-sweep of this jc
            half8 x2f[4];
#pragma unroll
            for (int mt = 0; mt < 4; ++mt)
                x2f[mt] = *(const half8*)&x2t[(rbase + mt * 16 + ol) * X2P + jc * 32 + q * 8];

            // W prefetch pipeline, distance 2 (k-chunk c = i*4 + jc)
            half8 bfa0 = wb[(size_t)((ibase + 0) * 4 + jc) * 512 + woff0];
            half8 bfa1 = wb[(size_t)((ibase + 0) * 4 + jc) * 512 + woff1];
            half8 bfb0 = wb[(size_t)((ibase + 1) * 4 + jc) * 512 + woff0];
            half8 bfb1 = wb[(size_t)((ibase + 1) * 4 + jc) * 512 + woff1];

            for (int i8 = 0; i8 < 8; ++i8) {
                half8 x1f[4];
#pragma unroll
                for (int mt = 0; mt < 4; ++mt)
                    x1f[mt] = *(const half8*)&x1th[(rbase + mt * 16 + ol) * X1P + i8 * 8];
#pragma unroll
                for (int ii = 0; ii < 8; ++ii) {
                    int il  = i8 * 8 + ii;
                    int ipl = (il < 62) ? (il + 2) : 63;
                    half8 bn0 = wb[(size_t)((ibase + ipl) * 4 + jc) * 512 + woff0];
                    half8 bn1 = wb[(size_t)((ibase + ipl) * 4 + jc) * 512 + woff1];
#pragma unroll
                    for (int mt = 0; mt < 4; ++mt) {
                        _Float16 sc = x1f[mt][ii];
                        half8 a = x2f[mt] * sc;    // 4 pk_mul shared by 2 MFMAs
                        acc[mt][0] = __builtin_amdgcn_mfma_f32_16x16x32_f16(a, bfa0, acc[mt][0], 0, 0, 0);
                        acc[mt][1] = __builtin_amdgcn_mfma_f32_16x16x32_f16(a, bfa1, acc[mt][1], 0, 0, 0);
                    }
                    bfa0 = bfb0; bfa1 = bfb1;
                    bfb0 = bn0;  bfb1 = bn1;
                }
            }
        }
    }

    // ---- epilogue: store y (f16) + per-o stats ----------------------------
    float sum0 = 0.f, sq0 = 0.f, sum1 = 0.f, sq1 = 0.f;
    int col0 = ntg0 * 16 + ol;
    int col1 = ntg1 * 16 + ol;
#pragma unroll
    for (int mt = 0; mt < 4; ++mt) {
#pragma unroll
        for (int r = 0; r < 4; ++r) {
            size_t row = (size_t)p * Bsz + m0 + rbase + mt * 16 + q * 4 + r;
            float v0 = acc[mt][0][r];
            sum0 += v0; sq0 += v0 * v0;
            yws[row * Fdim + col0] = (_Float16)v0;
            float v1e = acc[mt][1][r];
            sum1 += v1e; sq1 += v1e * v1e;
            yws[row * Fdim + col1] = (_Float16)v1e;
        }
    }
    sum0 += __shfl_xor(sum0, 16, 64);  sum0 += __shfl_xor(sum0, 32, 64);
    sq0  += __shfl_xor(sq0, 16, 64);   sq0  += __shfl_xor(sq0, 32, 64);
    sum1 += __shfl_xor(sum1, 16, 64);  sum1 += __shfl_xor(sum1, 32, 64);
    sq1  += __shfl_xor(sq1, 16, 64);   sq1  += __shfl_xor(sq1, 32, 64);
    if (q == 0) {
        atomicAdd(&ssum[p * Fdim + col0], sum0);
        atomicAdd(&ssq [p * Fdim + col0], sq0);
        atomicAdd(&ssum[p * Fdim + col1], sum1);
        atomicAdd(&ssq [p * Fdim + col1], sq1);
    }
}

// ---------------------------------------------------------------------------
// Kernel 3: BN (train-mode batch stats, biased var) + ReLU, f16 y -> fp32 out.
// ---------------------------------------------------------------------------
__global__ __launch_bounds__(256) void bnrelu(const _Float16* __restrict__ yws,
                                              const float* __restrict__ ssum,
                                              const float* __restrict__ ssq,
                                              const float* __restrict__ gamma,
                                              const float* __restrict__ beta,
                                              float* __restrict__ out) {
    __shared__ float gs[128], sh[128];
    size_t ebase = (size_t)blockIdx.x * 1024;
    int p = (int)(ebase >> 20);            // B*F = 2^20
    int t = threadIdx.x;
    if (t < 128) {
        float mean = ssum[p * Fdim + t] * (1.0f / 8192.0f);
        float var  = ssq [p * Fdim + t] * (1.0f / 8192.0f) - mean * mean;
        float g    = gamma[t] * rsqrtf(var + EPSI);
        gs[t] = g;
        sh[t] = beta[t] - g * mean;
    }
    __syncthreads();
    size_t e0 = ebase + (size_t)t * 4;
    int o0 = (int)(e0 & 127);
    half4t y = *(const half4t*)(yws + e0);
    float4t r;
#pragma unroll
    for (int l = 0; l < 4; ++l) {
        float v = fmaf(gs[o0 + l], (float)y[l], sh[o0 + l]);
        r[l] = v > 0.f ? v : 0.f;
    }
    *(float4t*)(out + e0) = r;
}

// ---------------------------------------------------------------------------
extern "C" void kernel_launch(void* const* d_in, const int* in_sizes, int n_in,
                              void* d_out, int out_size, void* d_ws, size_t ws_size,
                              hipStream_t stream) {
    const float* x     = (const float*)d_in[0];
    const float* W     = (const float*)d_in[1];
    // d_in[2] = linear bias b: mathematically cancelled by train-mode BN.
    const float* gamma = (const float*)d_in[3];
    const float* beta  = (const float*)d_in[4];
    float* out = (float*)d_out;

    char* ws = (char*)d_ws;
    _Float16* yws = (_Float16*)ws;                       // 6*8192*128*2 = 12,582,912 B
    _Float16* Wws = (_Float16*)(ws + 12582912);          // 128*16384*2  =  4,194,304 B
    float*    ssum = (float*)(ws + 16777216);            // 768 floats
    float*    ssq  = ssum + Pn * Fdim;                   // 768 floats

    (void)hipMemsetAsync(ssum, 0, 2 * Pn * Fdim * sizeof(float), stream);
    wprep<<<1024, 256, 0, stream>>>(W, Wws);
    gemm<<<768, 256, 0, stream>>>(x, Wws, yws, ssum, ssq);
    bnrelu<<<6144, 256, 0, stream>>>(yws, ssum, ssq, gamma, beta, out);
}